// Round 6
// baseline (377.044 us; speedup 1.0000x reference)
//
#include <hip/hip_runtime.h>
#include <math.h>

#define B 4
#define C 64
#define L 4096
#define OUTC 64
#define SCALE 10.0f
#define THRESH 1e-3f

// e_t geometry: 16 rows x 4100 ushorts (pad 4 -> row stride 2050 dwords
// == 2 mod 8, so the 4 quads' simultaneous ds_write_b16 rows (4 apart)
// land on bank-groups {0,8,16,24} -> conflict-free).
#define EROW 4100
#define SMEM_E_BYTES (16 * EROW * 2)              // 131200
#define SMEM_WSUM_OFF SMEM_E_BYTES                // 512 B: wsum[16][8]
#define SMEM_RINV_OFF (SMEM_E_BYTES + 512)        // 64 B: rinv[16]
#define SMEM_BYTES (SMEM_E_BYTES + 512 + 64)      // 131776

typedef float v4f __attribute__((ext_vector_type(4)));
typedef short bf16x8 __attribute__((ext_vector_type(8)));
typedef unsigned short us8 __attribute__((ext_vector_type(8)));
typedef unsigned short us4 __attribute__((ext_vector_type(4)));

__device__ __forceinline__ unsigned short f2bf(float x) {
    unsigned int u = __float_as_uint(x);
    u += 0x7fffu + ((u >> 16) & 1u);          // round-to-nearest-even
    return (unsigned short)(u >> 16);
}
__device__ __forceinline__ float bf2f(unsigned short h) {
    return __uint_as_float(((unsigned int)h) << 16);
}
__device__ __forceinline__ v4f mfma16(bf16x8 a, bf16x8 b, v4f c) {
    return __builtin_amdgcn_mfma_f32_16x16x32_bf16(a, b, c, 0, 0, 0);
}

// ---------------------------------------------------------------------------
// FRAGMENT-TILED operand layout (ushort units):
//   T(b,tile,chunk,lane,j) = ((b*256 + tile)*2 + chunk)*512 + lane*8 + j
// tile = col/16, chunk = c/32, lane = ((c&31)>>3)*16 + (col&15), j = c&7.
// Fragment load = base + lane*16B -> one contiguous 1 KB wave transaction.
//
// R5 CHANGE — COMPUTE-ONCE, LDS-STAGED EXP (f16), TWO CLEAN PHASES:
// Cross-round: every 2-pass-recompute schedule (R0 plain, R4 pipelined)
// sits at scores ~140-150us vs a ~90us component budget; replay-in-VGPR
// failed on occupancy (R1) and spill (R2/R3), but R3 PROVED the f16-exp
// replay path is numerically safe (absmax unchanged). The buffer that
// fits: LDS. 16 rows/block -> 16x4096 f16 = 128 KB < 160 KB pool.
//   Phase 1: A/B-prefetched MFMA+exp, each exp written ONCE to e_t as f16
//            (row sums in f32). MFMA count halves vs R0/R4; K read once.
//   Phase 2: after one barrier pair, a pure HBM write stream: LDS read ->
//            *rinv -> threshold -> NT v4f store. No Pt transpose, no
//            per-tile barriers (32 of them gone), no 2nd MFMA pass.
// Cost: 131.8 KB dynamic LDS -> 1 block/CU (2 waves/SIMD).
// XCD remap (batch b -> XCDs {2b,2b+1}) + NT output stores kept.
// ---------------------------------------------------------------------------

// ---------------------------------------------------------------------------
// Projection: p = l2norm(W2 @ leaky(W1 @ x)) per column, emitted as bf16
// hi/lo planes directly in the fragment-tiled layout above.
// 512 blocks x 256 threads; block->(which,b,ltile) decode is XCD-pinned.
// ---------------------------------------------------------------------------
__global__ void __launch_bounds__(256) proj_kernel(
    const float* __restrict__ q_in, const float* __restrict__ k_in,
    const float* __restrict__ W1, const float* __restrict__ W2,
    unsigned short* __restrict__ Qh, unsigned short* __restrict__ Ql,
    unsigned short* __restrict__ Kh, unsigned short* __restrict__ Kl)
{
    int bid   = blockIdx.x;        // 0..511
    int xcd   = bid & 7;
    int b     = xcd >> 1;
    int which = (bid >> 3) & 1;    // 0 = query, 1 = key
    int lt    = ((bid >> 4) << 1) | (xcd & 1);   // 0..63
    int l0    = lt << 6;
    int t     = threadIdx.x;
    int g     = t >> 6;            // 0..3  (owns channels [g*16, g*16+16))
    int l     = t & 63;

    const float* __restrict__ src =
        (which ? k_in : q_in) + (size_t)b * C * L + l0 + l;
    unsigned short* __restrict__ dh = which ? Kh : Qh;
    unsigned short* __restrict__ dl = which ? Kl : Ql;

    __shared__ float Ht[128][65];   // [h][l], pad 65 -> conflict-free
    __shared__ float red[4][64];

    float xr[C];
    #pragma unroll
    for (int c = 0; c < C; ++c)
        xr[c] = src[(size_t)c * L];

    // Stage 1: H[o][l] for o in [g*32, g*32+32)
    #pragma unroll 1
    for (int oo = 0; oo < 32; oo += 4) {
        #pragma unroll
        for (int u = 0; u < 4; ++u) {
            int o = g * 32 + oo + u;
            float h0 = 0.f, h1 = 0.f, h2 = 0.f, h3 = 0.f;
            #pragma unroll
            for (int c = 0; c < C; c += 4) {
                h0 = fmaf(W1[o * C + c + 0], xr[c + 0], h0);
                h1 = fmaf(W1[o * C + c + 1], xr[c + 1], h1);
                h2 = fmaf(W1[o * C + c + 2], xr[c + 2], h2);
                h3 = fmaf(W1[o * C + c + 3], xr[c + 3], h3);
            }
            float h = (h0 + h1) + (h2 + h3);
            Ht[o][l] = (h >= 0.0f) ? h : 0.01f * h;   // LeakyReLU(0.01)
        }
    }
    __syncthreads();

    // Stage 2: Y[o][l] for o in [g*16, g*16+16)
    float y[16];
    #pragma unroll
    for (int u = 0; u < 16; ++u) y[u] = 0.f;

    #pragma unroll 1
    for (int hh = 0; hh < 2 * C; hh += 16) {
        float hr[16];
        #pragma unroll
        for (int r = 0; r < 16; ++r)
            hr[r] = Ht[hh + r][l];
        #pragma unroll
        for (int u = 0; u < 16; ++u) {
            int o = g * 16 + u;
            #pragma unroll
            for (int h = 0; h < 16; ++h)
                y[u] = fmaf(W2[o * (2 * C) + hh + h], hr[h], y[u]);
        }
    }

    // l2norm over all 64 output channels (cross-group via LDS)
    float ss = 0.f;
    #pragma unroll
    for (int u = 0; u < 16; ++u) ss = fmaf(y[u], y[u], ss);
    red[g][l] = ss;
    __syncthreads();
    float tot = red[0][l] + red[1][l] + red[2][l] + red[3][l];
    float inv = 1.0f / fmaxf(sqrtf(tot), 1e-12f);

    // Emit bf16 hi/lo split in fragment-tiled layout.
    unsigned short hs[16], ls[16];
    #pragma unroll
    for (int u = 0; u < 16; ++u) {
        float val = y[u] * inv;
        hs[u] = f2bf(val);
        ls[u] = f2bf(val - bf2f(hs[u]));
    }
    {
        int col   = l0 + l;
        int tile  = col >> 4;
        int lnn   = col & 15;
        int chunk = g >> 1;
        int quad0 = (g & 1) * 2;
        size_t base0 = (((size_t)b * 256 + tile) * 2 + chunk) * 512
                     + (size_t)(quad0 * 16 + lnn) * 8;
        size_t base1 = base0 + 128;   // quad0+1 -> lane+16 -> +128 ushorts
        *(us8*)(dh + base0) = *(us8*)&hs[0];
        *(us8*)(dh + base1) = *(us8*)&hs[8];
        *(us8*)(dl + base0) = *(us8*)&ls[0];
        *(us8*)(dl + base1) = *(us8*)&ls[8];
    }
}

// Load the 4 K-plane fragments of absolute column-tile TILE into set SET.
#define LOADK(SET, TILE) do {                                            \
    size_t _kb = ((ktb + (size_t)(TILE)) * 2) * 512 + (size_t)lane * 8;  \
    SET##h0 = *(const bf16x8*)(Kh + _kb);                                \
    SET##l0 = *(const bf16x8*)(Kl + _kb);                                \
    SET##h1 = *(const bf16x8*)(Kh + _kb + 512);                          \
    SET##l1 = *(const bf16x8*)(Kl + _kb + 512);                          \
} while (0)

// ---------------------------------------------------------------------------
// Scores kernel: compute-once + LDS-staged f16 exp. 1024 blocks (XCD-pinned
// decode) x 512 threads (8 waves); 16 q-rows per block; 131.8 KB dynamic
// LDS -> 1 block/CU. S = Qh*Kh + Qh*Kl + Ql*Kh (lo*lo dropped); |S|<=10 ->
// fixed softmax shift 10 (exp(S-10)), row sums in f32.
// ---------------------------------------------------------------------------
__global__ void __launch_bounds__(512) scores_kernel(
    const unsigned short* __restrict__ Qh, const unsigned short* __restrict__ Ql,
    const unsigned short* __restrict__ Kh, const unsigned short* __restrict__ Kl,
    float* __restrict__ out)
{
    extern __shared__ unsigned char smem[];
    unsigned short* __restrict__ e_t  = (unsigned short*)smem;       // [16][EROW]
    float*          __restrict__ wsum = (float*)(smem + SMEM_WSUM_OFF); // [16][8]
    float*          __restrict__ rinv = (float*)(smem + SMEM_RINV_OFF); // [16]

    int bid  = blockIdx.x;          // 0..1023
    // XCD-locality decode: batch b = (bid&7)>>1.
    int xcd  = bid & 7;
    int b    = xcd >> 1;
    int r0   = (((bid >> 3) << 1) | (xcd & 1)) << 4;   // 16 rows, 0..4080
    int t    = threadIdx.x;
    int wave = t >> 6;
    int lane = t & 63;
    int quad = lane >> 4;
    int ln   = lane & 15;
    int wave16ln = wave * 16 + ln;
    int rowbase  = quad * 4;

    // A fragments (fragment-tiled): aQ[c0][hi/lo], one 16-row tile
    bf16x8 aQ[2][2];
    {
        size_t rowtile = (size_t)b * 256 + (r0 >> 4);
        #pragma unroll
        for (int c0 = 0; c0 < 2; ++c0) {
            size_t base = (rowtile * 2 + c0) * 512 + (size_t)lane * 8;
            aQ[c0][0] = *(const bf16x8*)(Qh + base);
            aQ[c0][1] = *(const bf16x8*)(Ql + base);
        }
    }

    const size_t ktb = (size_t)b * 256;

    // ---------------- phase 1: compute exp(S-10) ONCE into LDS ------------
    // STRIDED column assignment: iteration i covers tile i*8 + wave, i.e.
    // global cols i*128 + wave*16 + [0,16). Row sums accumulate in f32;
    // replay values stored as f16 (path validated by R3's absmax).
    v4f ps = (v4f){0.f, 0.f, 0.f, 0.f};
    bf16x8 Ah0, Al0, Ah1, Al1, Bh0, Bl0, Bh1, Bl1;

#define P1TILE(SET, COL0) do {                                           \
    v4f acc = (v4f){0.f, 0.f, 0.f, 0.f};                                 \
    acc = mfma16(aQ[0][0], SET##h0, acc);                                \
    acc = mfma16(aQ[0][1], SET##h0, acc);                                \
    acc = mfma16(aQ[0][0], SET##l0, acc);                                \
    acc = mfma16(aQ[1][0], SET##h1, acc);                                \
    acc = mfma16(aQ[1][1], SET##h1, acc);                                \
    acc = mfma16(aQ[1][0], SET##l1, acc);                                \
    _Pragma("unroll")                                                    \
    for (int r = 0; r < 4; ++r) {                                        \
        float ev = __expf(fmaf(SCALE, acc[r], -SCALE));                  \
        ps[r] += ev;                                                     \
        e_t[(rowbase + r) * EROW + (COL0) + wave16ln] =                  \
            __builtin_bit_cast(unsigned short, (_Float16)ev);            \
    }                                                                    \
} while (0)

    LOADK(A, wave);                      // i=0 tile
    #pragma unroll 1
    for (int i = 0; i < 32; i += 2) {
        LOADK(B, (i + 1) * 8 + wave);    // prefetch odd tile
        P1TILE(A, i * 128);              // compute even tile
        if (i + 2 < 32)
            LOADK(A, (i + 2) * 8 + wave);// prefetch next even tile
        P1TILE(B, (i + 1) * 128);        // compute odd tile
    }

    // reduce over the 16 ln-lanes (cols) per row, then across waves via LDS
    #pragma unroll
    for (int r = 0; r < 4; ++r) {
        float s = ps[r];
        s += __shfl_xor(s, 1);
        s += __shfl_xor(s, 2);
        s += __shfl_xor(s, 4);
        s += __shfl_xor(s, 8);
        if (ln == 0) wsum[(rowbase + r) * 8 + wave] = s;
    }
    __syncthreads();
    if (t < 16) {
        float s = 0.f;
        #pragma unroll
        for (int w = 0; w < 8; ++w) s += wsum[t * 8 + w];
        rinv[t] = 1.0f / s;
    }
    __syncthreads();

    // ---------------- phase 2: pure HBM write stream ----------------------
    // No MFMA, no K loads, no barriers: LDS f16 -> f32, *rinv, threshold,
    // NT v4f store. Thread t owns row t>>5, cols (t&31)*4 + 128*it.
    {
        float* __restrict__ outb = out + ((size_t)b * L + r0) * L;
        int row = t >> 5;
        int c0  = (t & 31) * 4;
        float ri = rinv[row];
        const unsigned short* __restrict__ erow = e_t + (size_t)row * EROW;
        float* __restrict__ orow = outb + (size_t)row * L;

        #pragma unroll 4
        for (int it = 0; it < 32; ++it) {
            int col = it * 128 + c0;
            us4 hv = *(const us4*)(erow + col);
            v4f o;
            #pragma unroll
            for (int j = 0; j < 4; ++j) {
                float w = (float)__builtin_bit_cast(_Float16,
                                                    (unsigned short)hv[j]) * ri;
                o[j] = (w > THRESH) ? w : 0.f;
            }
            __builtin_nontemporal_store(o, (v4f*)(orow + col));
        }
    }
}

// ---------------------------------------------------------------------------
extern "C" void kernel_launch(void* const* d_in, const int* in_sizes, int n_in,
                              void* d_out, int out_size, void* d_ws, size_t ws_size,
                              hipStream_t stream) {
    const float* query = (const float*)d_in[0];
    const float* key   = (const float*)d_in[1];
    const float* W1    = (const float*)d_in[2];
    const float* W2    = (const float*)d_in[3];
    float* out = (float*)d_out;

    // ws layout (ushorts): Qh | Ql | Kh | Kl, each B*L*OUTC = 1048576 elems
    unsigned short* Qh = (unsigned short*)d_ws;
    unsigned short* Ql = Qh + (size_t)B * L * OUTC;
    unsigned short* Kh = Ql + (size_t)B * L * OUTC;
    unsigned short* Kl = Kh + (size_t)B * L * OUTC;

    hipLaunchKernelGGL(proj_kernel, dim3(512), dim3(256), 0, stream,
                       query, key, W1, W2, Qh, Ql, Kh, Kl);
    hipLaunchKernelGGL(scores_kernel, dim3(1024), dim3(512), SMEM_BYTES, stream,
                       Qh, Ql, Kh, Kl, out);
}